// Round 1
// baseline (84.651 us; speedup 1.0000x reference)
//
#include <hip/hip_runtime.h>
#include <hip/hip_bf16.h>

// Problem constants (match reference)
#define B 8
#define S 512
#define D 768
#define N 512
#define MAX_W 16

// ---------------------------------------------------------------------------
// Kernel 1: logits[b,s] = dot(seq[b,s,:], att_w) + att_b[0]
// One wave (64 lanes) per row; 4 waves per 256-thread block.
// D=768 floats = 192 float4 = 64 lanes x 3 float4 each.
// ---------------------------------------------------------------------------
__global__ __launch_bounds__(256) void logits_kernel(
    const float* __restrict__ seq,
    const float* __restrict__ att_w,
    const float* __restrict__ att_b,
    float* __restrict__ logits)
{
    const int wave = threadIdx.x >> 6;
    const int lane = threadIdx.x & 63;
    const int row  = blockIdx.x * 4 + wave;          // in [0, B*S)

    const float4* seq4 = (const float4*)(seq + (size_t)row * D);
    const float4* w4   = (const float4*)att_w;

    float acc = 0.0f;
#pragma unroll
    for (int i = 0; i < 3; ++i) {
        float4 a = seq4[lane + 64 * i];
        float4 w = w4[lane + 64 * i];
        acc += a.x * w.x + a.y * w.y + a.z * w.z + a.w * w.w;
    }
    // wave-64 butterfly reduce
#pragma unroll
    for (int off = 32; off > 0; off >>= 1)
        acc += __shfl_xor(acc, off, 64);

    if (lane == 0) logits[row] = acc + att_b[0];
}

// ---------------------------------------------------------------------------
// Kernel 2: per span (one 192-thread block each):
//   width = end - start (inclusive count-1, in [0,15])
//   attn  = softmax(logits[b, start .. start+width])   (exact over valid)
//   out[b,n,:] = sum_w attn[w] * seq[b, start+w, :]
// Each thread owns one float4 of the D=768 output row.
// All mask predicates are block-uniform (no divergence).
// ---------------------------------------------------------------------------
__global__ __launch_bounds__(192) void span_kernel(
    const float* __restrict__ seq,
    const int*   __restrict__ spans,
    const float* __restrict__ logits,
    float* __restrict__ out)
{
    const int span  = blockIdx.x;        // 0 .. B*N-1
    const int b     = span >> 9;         // N = 512
    const int start = spans[span * 2 + 0];
    const int end   = spans[span * 2 + 1];
    const int width = end - start;       // valid count - 1, in [0, 15]

    // --- softmax over valid logits (redundant per thread; uniform loads) ---
    const float* lrow = logits + b * S + start;
    float wgt[MAX_W];
    float m = -1e30f;
#pragma unroll
    for (int i = 0; i < MAX_W; ++i) {
        // start+15 < S always holds for this problem, so the load is safe.
        float l = lrow[i];
        wgt[i] = l;
        if (i <= width) m = fmaxf(m, l);
    }
    float sum = 0.0f;
#pragma unroll
    for (int i = 0; i < MAX_W; ++i) {
        float e = (i <= width) ? __expf(wgt[i] - m) : 0.0f;
        wgt[i] = e;
        sum += e;
    }
    const float inv = 1.0f / sum;   // TINY=1e-13 in ref is negligible vs threshold

    // --- weighted sum over valid rows ---
    const float4* seqb = (const float4*)(seq + ((size_t)b * S + start) * D);
    const int tid = threadIdx.x;         // 0 .. 191
    float4 acc = make_float4(0.f, 0.f, 0.f, 0.f);
#pragma unroll
    for (int i = 0; i < MAX_W; ++i) {
        if (i <= width) {                // block-uniform branch
            float4 v = seqb[i * (D / 4) + tid];
            float w = wgt[i];
            acc.x += w * v.x;
            acc.y += w * v.y;
            acc.z += w * v.z;
            acc.w += w * v.w;
        }
    }
    acc.x *= inv; acc.y *= inv; acc.z *= inv; acc.w *= inv;

    float4* out4 = (float4*)(out + (size_t)span * D);
    out4[tid] = acc;
}

extern "C" void kernel_launch(void* const* d_in, const int* in_sizes, int n_in,
                              void* d_out, int out_size, void* d_ws, size_t ws_size,
                              hipStream_t stream) {
    const float* seq    = (const float*)d_in[0];   // (B,S,D) fp32
    const int*   spans  = (const int*)d_in[1];     // (B,N,2) int32
    const float* att_w  = (const float*)d_in[2];   // (D,)
    const float* att_b  = (const float*)d_in[3];   // (1,)
    float* out = (float*)d_out;                    // (B,N,D) fp32
    float* logits = (float*)d_ws;                  // B*S floats = 16 KB

    // Kernel 1: 4096 rows, 4 rows per 256-thread block
    logits_kernel<<<(B * S) / 4, 256, 0, stream>>>(seq, att_w, att_b, logits);

    // Kernel 2: one block per span
    span_kernel<<<B * N, 192, 0, stream>>>(seq, spans, logits, out);
}

// Round 2
// 80.095 us; speedup vs baseline: 1.0569x; 1.0569x over previous
//
#include <hip/hip_runtime.h>
#include <hip/hip_bf16.h>

// Problem constants (match reference)
#define B 8
#define S 512
#define D 768
#define N 512
#define MAX_W 16

// ---------------------------------------------------------------------------
// Kernel 1: logits[b,s] = dot(seq[b,s,:], att_w) + att_b[0]
// One wave (64 lanes) per row; 4 waves per 256-thread block.
// D=768 floats = 192 float4 = 64 lanes x 3 float4 each.
// ---------------------------------------------------------------------------
__global__ __launch_bounds__(256) void logits_kernel(
    const float* __restrict__ seq,
    const float* __restrict__ att_w,
    const float* __restrict__ att_b,
    float* __restrict__ logits)
{
    const int wave = threadIdx.x >> 6;
    const int lane = threadIdx.x & 63;
    const int row  = blockIdx.x * 4 + wave;          // in [0, B*S)

    const float4* seq4 = (const float4*)(seq + (size_t)row * D);
    const float4* w4   = (const float4*)att_w;

    float acc = 0.0f;
#pragma unroll
    for (int i = 0; i < 3; ++i) {
        float4 a = seq4[lane + 64 * i];
        float4 w = w4[lane + 64 * i];
        acc += a.x * w.x + a.y * w.y + a.z * w.z + a.w * w.w;
    }
    // wave-64 butterfly reduce
#pragma unroll
    for (int off = 32; off > 0; off >>= 1)
        acc += __shfl_xor(acc, off, 64);

    if (lane == 0) logits[row] = acc + att_b[0];
}

// ---------------------------------------------------------------------------
// Kernel 2: per span (one 192-thread block each):
//   width = end - start (inclusive count-1, in [0,15])
//   attn  = softmax(logits[b, start .. start+width])   (exact over valid)
//   out[b,n,:] = sum_w attn[w] * seq[b, start+w, :]
// Each thread owns one float4 of the D=768 output row.
// All mask predicates are block-uniform (no divergence).
//
// XCD-locality swizzle: block bid -> span (bid%8)*512 + bid/8. With the
// empirical bid%8 -> XCD round-robin, XCD x then touches ONLY batch x's
// seq slice (1.57 MB), which fits its private 4 MB L2 (unswizzled working
// set is all 12.6 MB per XCD -> constant L2 capacity misses).
// ---------------------------------------------------------------------------
__global__ __launch_bounds__(192) void span_kernel(
    const float* __restrict__ seq,
    const int*   __restrict__ spans,
    const float* __restrict__ logits,
    float* __restrict__ out)
{
    const int bid   = blockIdx.x;                    // 0 .. B*N-1 (4096)
    const int span  = (bid & 7) * (B * N / 8) + (bid >> 3);   // bijective: 4096 % 8 == 0
    const int b     = span >> 9;                     // N = 512
    const int start = spans[span * 2 + 0];
    const int end   = spans[span * 2 + 1];
    const int width = end - start;                   // valid count - 1, in [0, 15]

    // --- softmax over valid logits (redundant per thread; uniform loads) ---
    const float* lrow = logits + b * S + start;
    float wgt[MAX_W];
    float m = -1e30f;
#pragma unroll
    for (int i = 0; i < MAX_W; ++i) {
        // start+15 < S always holds for this problem, so the load is safe.
        float l = lrow[i];
        wgt[i] = l;
        if (i <= width) m = fmaxf(m, l);
    }
    float sum = 0.0f;
#pragma unroll
    for (int i = 0; i < MAX_W; ++i) {
        float e = (i <= width) ? __expf(wgt[i] - m) : 0.0f;
        wgt[i] = e;
        sum += e;
    }
    const float inv = 1.0f / sum;   // TINY=1e-13 in ref is negligible vs threshold

    // --- weighted sum over valid rows ---
    const float4* seqb = (const float4*)(seq + ((size_t)b * S + start) * D);
    const int tid = threadIdx.x;         // 0 .. 191
    float4 acc = make_float4(0.f, 0.f, 0.f, 0.f);
#pragma unroll
    for (int i = 0; i < MAX_W; ++i) {
        if (i <= width) {                // block-uniform branch
            float4 v = seqb[i * (D / 4) + tid];
            float w = wgt[i];
            acc.x += w * v.x;
            acc.y += w * v.y;
            acc.z += w * v.z;
            acc.w += w * v.w;
        }
    }
    acc.x *= inv; acc.y *= inv; acc.z *= inv; acc.w *= inv;

    float4* out4 = (float4*)(out + (size_t)span * D);
    out4[tid] = acc;
}

extern "C" void kernel_launch(void* const* d_in, const int* in_sizes, int n_in,
                              void* d_out, int out_size, void* d_ws, size_t ws_size,
                              hipStream_t stream) {
    const float* seq    = (const float*)d_in[0];   // (B,S,D) fp32
    const int*   spans  = (const int*)d_in[1];     // (B,N,2) int32
    const float* att_w  = (const float*)d_in[2];   // (D,)
    const float* att_b  = (const float*)d_in[3];   // (1,)
    float* out = (float*)d_out;                    // (B,N,D) fp32
    float* logits = (float*)d_ws;                  // B*S floats = 16 KB

    // Kernel 1: 4096 rows, 4 rows per 256-thread block
    logits_kernel<<<(B * S) / 4, 256, 0, stream>>>(seq, att_w, att_b, logits);

    // Kernel 2: one block per span (XCD-swizzled inside)
    span_kernel<<<B * N, 192, 0, stream>>>(seq, spans, logits, out);
}